// Round 16
// baseline (157.077 us; speedup 1.0000x reference)
//
#include <hip/hip_runtime.h>
#include <math.h>

#define BB 2
#define II 128
#define JJ 512
#define CC 256
#define NEL (BB*II*JJ)   // 131072
#define NINF (-INFINITY)
#define K10 4.5399929762484854e-5f   // exp(-10)
#define RING 12

typedef float f32x4 __attribute__((ext_vector_type(4)));

// ---------------- DPP wave64 primitives ----------------
template<int CTRL, int RM = 0xf, int BM = 0xf, bool BC = true>
__device__ __forceinline__ float dppf(float x) {
    return __int_as_float(__builtin_amdgcn_update_dpp(
        0, __float_as_int(x), CTRL, RM, BM, BC));
}
__device__ __forceinline__ float wscan_incl(float x) {
    x += dppf<0x111>(x);              // row_shr:1
    x += dppf<0x112>(x);              // row_shr:2
    x += dppf<0x114>(x);              // row_shr:4
    x += dppf<0x118>(x);              // row_shr:8
    x += dppf<0x142, 0xa>(x);         // row_bcast:15 -> rows 1,3
    x += dppf<0x143, 0xc>(x);         // row_bcast:31 -> rows 2,3
    return x;
}
__device__ __forceinline__ float lane_shr1(float x) { return dppf<0x138>(x); }
__device__ __forceinline__ float bcast63(float x) {
    return __int_as_float(__builtin_amdgcn_readlane(__float_as_int(x), 63));
}

// in-lane inclusive prefix sum, tree form (depth 3)
__device__ __forceinline__ void tree_prefix8(const float x[8], float P[8]) {
    float t[8];
    t[0] = x[0];
    #pragma unroll
    for (int q = 1; q < 8; ++q) t[q] = x[q] + x[q-1];
    float u[8];
    u[0] = t[0]; u[1] = t[1];
    #pragma unroll
    for (int q = 2; q < 8; ++q) u[q] = t[q] + t[q-2];
    P[0] = u[0]; P[1] = u[1]; P[2] = u[2]; P[3] = u[3];
    #pragma unroll
    for (int q = 4; q < 8; ++q) P[q] = u[q] + u[q-4];
}

__device__ __forceinline__ void loadrow8(const float* p, float v[8]) {
    float4 a = *reinterpret_cast<const float4*>(p);
    float4 b = *reinterpret_cast<const float4*>(p + 4);
    v[0]=a.x; v[1]=a.y; v[2]=a.z; v[3]=a.w;
    v[4]=b.x; v[5]=b.y; v[6]=b.z; v[7]=b.w;
}
__device__ __forceinline__ void storerow8(float* __restrict__ p, const float v[8]) {
    *reinterpret_cast<float4*>(p)     = make_float4(v[0],v[1],v[2],v[3]);
    *reinterpret_cast<float4*>(p + 4) = make_float4(v[4],v[5],v[6],v[7]);
}

// ---------------- hand-held vmem ops (invisible to SIInsertWaitcnts) ----------------
__device__ __forceinline__ void aload2(f32x4 &d0, f32x4 &d1, const float* p) {
    asm volatile("global_load_dwordx4 %0, %2, off\n\t"
                 "global_load_dwordx4 %1, %2, off offset:16"
                 : "=&v"(d0), "=&v"(d1) : "v"(p) : "memory");
}
__device__ __forceinline__ void astore2(f32x4 d0, f32x4 d1, float* p) {
    asm volatile("global_store_dwordx4 %2, %0, off\n\t"
                 "global_store_dwordx4 %2, %1, off offset:16"
                 :: "v"(d0), "v"(d1), "v"(p) : "memory");
}
template<int N> __device__ __forceinline__ void waitcnt_vm() {
    asm volatile("s_waitcnt vmcnt(%0)" :: "i"(N) : "memory");
}
__device__ __forceinline__ void waitcnt_lgkm0() {
    asm volatile("s_waitcnt lgkmcnt(0)" ::: "memory");
}

// ---------------- energy: tiled outer-product GEMM (R7 form) ----------------
__global__ __launch_bounds__(256) void energy_kernel(
        const float* __restrict__ text, const float* __restrict__ mel,
        const float* __restrict__ noise, const float* __restrict__ ratio,
        float* __restrict__ e) {
    __shared__ float melS[64][65];
    __shared__ float texS[8][65];
    int b  = blockIdx.x;
    int i0 = blockIdx.y * 8;
    int j0 = blockIdx.z * 64;
    int t = threadIdx.x;
    int jj = t & 63, ig = t >> 6;
    float acc0 = 0.f, acc1 = 0.f;
    for (int cc = 0; cc < CC; cc += 64) {
        #pragma unroll
        for (int k = 0; k < 4; ++k) {
            int idx = t + k * 256;
            int row = idx >> 4, seg = idx & 15;
            float4 v = *reinterpret_cast<const float4*>(
                mel + (size_t)(b * JJ + j0 + row) * CC + cc + seg * 4);
            melS[row][seg*4+0] = v.x; melS[row][seg*4+1] = v.y;
            melS[row][seg*4+2] = v.z; melS[row][seg*4+3] = v.w;
        }
        if (t < 128) {
            int row = t >> 4, seg = t & 15;
            float4 v = *reinterpret_cast<const float4*>(
                text + (size_t)(b * II + i0 + row) * CC + cc + seg * 4);
            texS[row][seg*4+0] = v.x; texS[row][seg*4+1] = v.y;
            texS[row][seg*4+2] = v.z; texS[row][seg*4+3] = v.w;
        }
        __syncthreads();
        #pragma unroll 8
        for (int c = 0; c < 64; ++c) {
            float m = melS[jj][c];
            acc0 = fmaf(m, texS[ig*2+0][c], acc0);
            acc1 = fmaf(m, texS[ig*2+1][c], acc1);
        }
        __syncthreads();
    }
    float temp = 0.1f + 0.9f * ratio[0];
    float rtmp = 1.0f / temp;
    int r0 = (b * II + i0 + ig*2 + 0) * JJ + j0 + jj;
    int r1 = (b * II + i0 + ig*2 + 1) * JJ + j0 + jj;
    e[r0] = (acc0 * (1.0f/256.0f) + noise[r0]) * rtmp;
    e[r1] = (acc1 * (1.0f/256.0f) + noise[r1]) * rtmp;
}

// ---------------- dscan (R7 form) ----------------
__global__ __launch_bounds__(64) void dscan_kernel(
        const float* __restrict__ e, float* __restrict__ Ee,
        float* __restrict__ Wa, float* __restrict__ Wb) {
    int row = blockIdx.x;
    int lane = threadIdx.x;
    float v[8];
    loadrow8(e + row * JJ + lane * 8, v);
    float m = v[0];
    #pragma unroll
    for (int q = 1; q < 8; ++q) m = fmaxf(m, v[q]);
    #pragma unroll
    for (int d = 1; d < 64; d <<= 1) m = fmaxf(m, __shfl_xor(m, d, 64));
    float x[8];
    #pragma unroll
    for (int q = 0; q < 8; ++q) x[q] = __expf(v[q] - m);
    storerow8(Ee + row * JJ + lane * 8, x);
    float run = 0.f, P[8];
    #pragma unroll
    for (int q = 0; q < 8; ++q) { run += x[q]; P[q] = run; }
    float sc = wscan_incl(run);
    float cp = lane_shr1(sc);
    float run2 = 0.f, S[8];
    #pragma unroll
    for (int q = 7; q >= 0; --q) { run2 += x[q]; S[q] = run2; }
    float sd = run2;
    #pragma unroll
    for (int d = 1; d < 64; d <<= 1) { float o = __shfl_down(sd, d, 64); sd += (lane + d < 64) ? o : 0.0f; }
    float cs = __shfl_down(sd, 1, 64); if (lane == 63) cs = 0.f;
    float wa[8], wb[8];
    #pragma unroll
    for (int q = 0; q < 8; ++q) {
        wa[q] = 1.0f / (S[q] + cs);
        wb[q] = 1.0f / (P[q] + cp);
    }
    storerow8(Wa + row * JJ + lane * 8, wa);
    storerow8(Wb + row * JJ + lane * 8, wb);
}

// ======================= scan_ab: producer/consumer, REGISTER-load producers =======================
// R3/R4/R15 all supplied rows via global_load_lds and all ran ~1250-1300 cy/row
// (three schedules, incl. 4 independent producer waves) => per-CU LDS-DMA engine
// serializes at ~1250cy/row. Register loads run ~800cy/step => producers now use
// plain asm global loads (per-wave queues) + ds_write_b128. Each producer
// double-buffers 2 rows: [ld row k][ld row k+4] wait vmcnt(4) -> ds_write k ->
// lgkmcnt(0) (closes WAR on buffer reuse) -> flag -> [ld row k+8] ...
// Supply rate ~ L/8 across 4 producers. Consumer identical to R15 (verified):
// no loads in its vmcnt queue (2 stores/step, vmcnt(14) = ack/7 pacing),
// flag-poll per row, LDS ring depth 12. Only barrier = init.

template<bool NORM>
__device__ __forceinline__ void astepL(
    int i, int lane, int off,
    const float (&pin)[8], float (&pout)[8], float& c,
    float (*ringE)[JJ], float (*ringW)[JJ],
    volatile int* vflg, volatile int* vdone,
    float* __restrict__ paB, float* ldsC)
{
    {
        f32x4 s0 = {pin[0], pin[1], pin[2], pin[3]};
        f32x4 s1 = {pin[4], pin[5], pin[6], pin[7]};
        astore2(s0, s1, paB + (size_t)(i - 1) * JJ + off);   // pin holds row i-1
    }
    if (lane == 0) { ldsC[i - 1] = c; *vdone = i - 1; }
    int s = i % RING;
    while (vflg[s] != i) __builtin_amdgcn_s_sleep(1);
    waitcnt_vm<14>();                       // stores 7 steps old acked (P-ring 8)
    __builtin_amdgcn_sched_barrier(0);      // rule #18
    float CE[8], CW[8];
    loadrow8(&ringE[s][off], CE);
    loadrow8(&ringW[s][off], CW);

    float pup = lane_shr1(pin[7]);
    float y[8];
    y[0] = pup * CW[0];
    #pragma unroll
    for (int q = 1; q < 8; ++q) y[q] = pin[q-1] * CW[q];
    float zz[8];
    #pragma unroll
    for (int q = 0; q < 7; ++q) zz[q] = pin[q];
    zz[7] = (lane == 63) ? 0.0f : pin[7];
    float Y[8], Z[8];
    tree_prefix8(y, Y);
    tree_prefix8(zz, Z);
    float sy = wscan_incl(Y[7]);
    float sz = wscan_incl(Z[7]);
    float oy = lane_shr1(sy);
    float oz = lane_shr1(sz);
    float T  = bcast63(sz);
    #pragma unroll
    for (int q = 0; q < 8; ++q) {
        float S1 = oy + Y[q];                              // incl prefix of y
        float S2 = fmaxf(T - (oz + Z[q]) + zz[q], 0.0f);   // incl suffix of z
        pout[q] = fmaf(CE[q], S1, K10 * S2);
    }
    if (NORM) {
        float Tc = fmaxf(T, 1e-30f);
        float rT = __builtin_amdgcn_rcpf(Tc);
        c += __logf(Tc);
        #pragma unroll
        for (int q = 0; q < 8; ++q) pout[q] *= rT;
    }
}

template<bool NORM>
__device__ __forceinline__ void bstepL(
    int i, int lane, int off,
    const float (&pin)[8], float (&pout)[8], float& c,
    float (*ringE)[JJ], float (*ringW)[JJ],
    volatile int* vflg, volatile int* vdone,
    float* __restrict__ pbB, float* ldsC)
{
    {
        f32x4 s0 = {pin[0], pin[1], pin[2], pin[3]};
        f32x4 s1 = {pin[4], pin[5], pin[6], pin[7]};
        astore2(s0, s1, pbB + (size_t)(i + 1) * JJ + off);   // pin holds row i+1
    }
    int q126 = 126 - i;                     // sequence index
    if (lane == 0) { ldsC[i + 1] = c; *vdone = q126 - 1; }
    int s = q126 % RING;
    while (vflg[s] != q126) __builtin_amdgcn_s_sleep(1);
    waitcnt_vm<14>();
    __builtin_amdgcn_sched_barrier(0);
    float tE[8], tW[8], CE[8], CW[8];
    loadrow8(&ringE[s][504 - off], tE);     // reversed: CE[q] = row[511-8*lane-q]
    loadrow8(&ringW[s][504 - off], tW);
    #pragma unroll
    for (int q = 0; q < 8; ++q) { CE[q] = tE[7-q]; CW[q] = tW[7-q]; }

    float pup = lane_shr1(pin[7]);
    float pn[8];
    pn[0] = pup;
    #pragma unroll
    for (int q = 1; q < 8; ++q) pn[q] = pin[q-1];
    float w[8];
    #pragma unroll
    for (int q = 0; q < 8; ++q) w[q] = pn[q] * CW[q];
    float W[8], N[8];
    tree_prefix8(w, W);
    tree_prefix8(pn, N);
    float sw = wscan_incl(W[7]);
    float sn = wscan_incl(N[7]);
    float ow = lane_shr1(sw);
    float on = lane_shr1(sn);
    float T  = bcast63(sn);
    #pragma unroll
    for (int q = 0; q < 8; ++q) {
        float QA = ow + W[q];                    // incl prefix of w
        float QB = fmaxf(T - (on + N[q]), 0.0f); // excl suffix of pn
        pout[q] = fmaf(CE[q], QA, K10 * QB);
    }
    if (NORM) {
        float Tc = fmaxf(T, 1e-30f);
        float rT = __builtin_amdgcn_rcpf(Tc);
        c += __logf(Tc);
        #pragma unroll
        for (int q = 0; q < 8; ++q) pout[q] *= rT;
    }
}

__global__ __launch_bounds__(320, 1) void scan_ab_kernel(
        const float* __restrict__ Ee, const float* __restrict__ Wa,
        const float* __restrict__ Wb,
        float* __restrict__ pa, float* __restrict__ pb,
        float* __restrict__ ca, float* __restrict__ cb) {
    __shared__ float ringE[RING][JJ];
    __shared__ float ringW[RING][JJ];
    __shared__ int   flg[RING];
    __shared__ int   done;
    __shared__ float ldsC[II];
    int b = blockIdx.x >> 1, dir = blockIdx.x & 1;
    int t = threadIdx.x;
    int lane = t & 63, w = t >> 6;
    size_t base = (size_t)b * II * JJ;
    const float* EeB = Ee + base;
    const float* WB  = (dir == 0 ? Wa : Wb) + base;
    volatile int* vflg  = flg;
    volatile int* vdone = &done;

    if (t < RING) flg[t] = -1;
    if (t == RING) done = -1;
    __syncthreads();    // the ONLY barrier

    if (w >= 1) {
        // -------- producer waves 1..4: register loads, own vmcnt queues --------
        int nk = (dir == 0) ? 128 : 127;
        int off8 = lane * 8;
        int k = w - 1;
        f32x4 A0,A1,A2,A3, C0,C1,C2,C3;
        // prologue: rows k and k+4 in flight
        if (k < nk) {
            int r = (dir == 0) ? k : (126 - k);
            aload2(A0, A1, EeB + (size_t)r * JJ + off8);
            aload2(A2, A3, WB  + (size_t)r * JJ + off8);
        }
        if (k + 4 < nk) {
            int r = (dir == 0) ? (k + 4) : (126 - (k + 4));
            aload2(C0, C1, EeB + (size_t)r * JJ + off8);
            aload2(C2, C3, WB  + (size_t)r * JJ + off8);
        }
        while (k < nk) {
            // phase A: row k resident when the 4 younger (phase-C) ops remain
            if (k + 4 < nk) waitcnt_vm<4>(); else waitcnt_vm<0>();
            __builtin_amdgcn_sched_barrier(0);
            if (k >= RING) { while (*vdone < k - RING) __builtin_amdgcn_s_sleep(2); }
            int s = k % RING;
            *reinterpret_cast<f32x4*>(&ringE[s][off8])     = A0;
            *reinterpret_cast<f32x4*>(&ringE[s][off8 + 4]) = A1;
            *reinterpret_cast<f32x4*>(&ringW[s][off8])     = A2;
            *reinterpret_cast<f32x4*>(&ringW[s][off8 + 4]) = A3;
            waitcnt_lgkm0();                      // ds_writes consumed A regs (WAR)
            if (lane == 0) vflg[s] = k;
            if (k + 8 < nk) {
                int r = (dir == 0) ? (k + 8) : (126 - (k + 8));
                aload2(A0, A1, EeB + (size_t)r * JJ + off8);
                aload2(A2, A3, WB  + (size_t)r * JJ + off8);
            }
            k += 4;
            if (k >= nk) break;
            // phase C: row k (old k+4)
            if (k + 4 < nk) waitcnt_vm<4>(); else waitcnt_vm<0>();
            __builtin_amdgcn_sched_barrier(0);
            if (k >= RING) { while (*vdone < k - RING) __builtin_amdgcn_s_sleep(2); }
            s = k % RING;
            *reinterpret_cast<f32x4*>(&ringE[s][off8])     = C0;
            *reinterpret_cast<f32x4*>(&ringE[s][off8 + 4]) = C1;
            *reinterpret_cast<f32x4*>(&ringW[s][off8])     = C2;
            *reinterpret_cast<f32x4*>(&ringW[s][off8 + 4]) = C3;
            waitcnt_lgkm0();
            if (lane == 0) vflg[s] = k;
            if (k + 8 < nk) {
                int r = (dir == 0) ? (k + 8) : (126 - (k + 8));
                aload2(C0, C1, EeB + (size_t)r * JJ + off8);
                aload2(C2, C3, WB  + (size_t)r * JJ + off8);
            }
            k += 4;
        }
        return;
    }

    // -------- consumer wave 0 (identical to R15, verified) --------
    int off = lane * 8;
    float P0[8],P1[8],P2[8],P3[8],P4[8],P5[8],P6[8],P7[8], c = 0.0f;

    if (dir == 0) {
        float* paB = pa + base; float* caB = ca + b * II;
        while (vflg[0] != 0) __builtin_amdgcn_s_sleep(1);
        float e0r[8];
        loadrow8(&ringE[0][off], e0r);
        float wa00 = ringW[0][0];
        #pragma unroll
        for (int q = 0; q < 8; ++q) P0[q] = e0r[q] * wa00;   // row 0
        // steps 1..7
        astepL<true >(1, lane, off, P0, P1, c, ringE, ringW, vflg, vdone, paB, ldsC);
        astepL<false>(2, lane, off, P1, P2, c, ringE, ringW, vflg, vdone, paB, ldsC);
        astepL<false>(3, lane, off, P2, P3, c, ringE, ringW, vflg, vdone, paB, ldsC);
        astepL<false>(4, lane, off, P3, P4, c, ringE, ringW, vflg, vdone, paB, ldsC);
        astepL<true >(5, lane, off, P4, P5, c, ringE, ringW, vflg, vdone, paB, ldsC);
        astepL<false>(6, lane, off, P5, P6, c, ringE, ringW, vflg, vdone, paB, ldsC);
        astepL<false>(7, lane, off, P6, P7, c, ringE, ringW, vflg, vdone, paB, ldsC);
        #pragma unroll 1
        for (int d = 0; d < 14; ++d) {        // steps 8..119
            int i = 8 + 8 * d;
            astepL<false>(i+0, lane, off, P7, P0, c, ringE, ringW, vflg, vdone, paB, ldsC);
            astepL<true >(i+1, lane, off, P0, P1, c, ringE, ringW, vflg, vdone, paB, ldsC);
            astepL<false>(i+2, lane, off, P1, P2, c, ringE, ringW, vflg, vdone, paB, ldsC);
            astepL<false>(i+3, lane, off, P2, P3, c, ringE, ringW, vflg, vdone, paB, ldsC);
            astepL<false>(i+4, lane, off, P3, P4, c, ringE, ringW, vflg, vdone, paB, ldsC);
            astepL<true >(i+5, lane, off, P4, P5, c, ringE, ringW, vflg, vdone, paB, ldsC);
            astepL<false>(i+6, lane, off, P5, P6, c, ringE, ringW, vflg, vdone, paB, ldsC);
            astepL<false>(i+7, lane, off, P6, P7, c, ringE, ringW, vflg, vdone, paB, ldsC);
        }
        // steps 120..127
        astepL<false>(120, lane, off, P7, P0, c, ringE, ringW, vflg, vdone, paB, ldsC);
        astepL<true >(121, lane, off, P0, P1, c, ringE, ringW, vflg, vdone, paB, ldsC);
        astepL<false>(122, lane, off, P1, P2, c, ringE, ringW, vflg, vdone, paB, ldsC);
        astepL<false>(123, lane, off, P2, P3, c, ringE, ringW, vflg, vdone, paB, ldsC);
        astepL<false>(124, lane, off, P3, P4, c, ringE, ringW, vflg, vdone, paB, ldsC);
        astepL<true >(125, lane, off, P4, P5, c, ringE, ringW, vflg, vdone, paB, ldsC);
        astepL<false>(126, lane, off, P5, P6, c, ringE, ringW, vflg, vdone, paB, ldsC);
        astepL<false>(127, lane, off, P6, P7, c, ringE, ringW, vflg, vdone, paB, ldsC);
        storerow8(paB + (size_t)127 * JJ + off, P7);
        if (lane == 0) ldsC[127] = c;
        waitcnt_vm<0>();                       // drain asm stores before endpgm
        caB[lane]      = ldsC[lane];
        caB[lane + 64] = ldsC[lane + 64];
    } else {
        float* pbB = pb + base; float* cbB = cb + b * II;
        #pragma unroll
        for (int q = 0; q < 8; ++q) P0[q] = 0.0f;
        P0[0] = (lane == 0) ? 1.0f : 0.0f;   // row 127 (j'=0 <-> orig j=J-1)
        // steps 126..120
        bstepL<true >(126, lane, off, P0, P1, c, ringE, ringW, vflg, vdone, pbB, ldsC);
        bstepL<false>(125, lane, off, P1, P2, c, ringE, ringW, vflg, vdone, pbB, ldsC);
        bstepL<false>(124, lane, off, P2, P3, c, ringE, ringW, vflg, vdone, pbB, ldsC);
        bstepL<false>(123, lane, off, P3, P4, c, ringE, ringW, vflg, vdone, pbB, ldsC);
        bstepL<true >(122, lane, off, P4, P5, c, ringE, ringW, vflg, vdone, pbB, ldsC);
        bstepL<false>(121, lane, off, P5, P6, c, ringE, ringW, vflg, vdone, pbB, ldsC);
        bstepL<false>(120, lane, off, P6, P7, c, ringE, ringW, vflg, vdone, pbB, ldsC);
        #pragma unroll 1
        for (int d = 0; d < 14; ++d) {        // steps 119..8
            int i = 119 - 8 * d;
            bstepL<false>(i-0, lane, off, P7, P0, c, ringE, ringW, vflg, vdone, pbB, ldsC);
            bstepL<true >(i-1, lane, off, P0, P1, c, ringE, ringW, vflg, vdone, pbB, ldsC);
            bstepL<false>(i-2, lane, off, P1, P2, c, ringE, ringW, vflg, vdone, pbB, ldsC);
            bstepL<false>(i-3, lane, off, P2, P3, c, ringE, ringW, vflg, vdone, pbB, ldsC);
            bstepL<false>(i-4, lane, off, P3, P4, c, ringE, ringW, vflg, vdone, pbB, ldsC);
            bstepL<true >(i-5, lane, off, P4, P5, c, ringE, ringW, vflg, vdone, pbB, ldsC);
            bstepL<false>(i-6, lane, off, P5, P6, c, ringE, ringW, vflg, vdone, pbB, ldsC);
            bstepL<false>(i-7, lane, off, P6, P7, c, ringE, ringW, vflg, vdone, pbB, ldsC);
        }
        // steps 7..0
        bstepL<false>(7, lane, off, P7, P0, c, ringE, ringW, vflg, vdone, pbB, ldsC);
        bstepL<true >(6, lane, off, P0, P1, c, ringE, ringW, vflg, vdone, pbB, ldsC);
        bstepL<false>(5, lane, off, P1, P2, c, ringE, ringW, vflg, vdone, pbB, ldsC);
        bstepL<false>(4, lane, off, P2, P3, c, ringE, ringW, vflg, vdone, pbB, ldsC);
        bstepL<false>(3, lane, off, P3, P4, c, ringE, ringW, vflg, vdone, pbB, ldsC);
        bstepL<true >(2, lane, off, P4, P5, c, ringE, ringW, vflg, vdone, pbB, ldsC);
        bstepL<false>(1, lane, off, P5, P6, c, ringE, ringW, vflg, vdone, pbB, ldsC);
        bstepL<false>(0, lane, off, P6, P7, c, ringE, ringW, vflg, vdone, pbB, ldsC);
        storerow8(pbB + off, P7);           // row 0 (reversed layout)
        if (lane == 0) ldsC[0] = c;
        waitcnt_vm<0>();
        cbB[lane]      = ldsC[lane];
        cbB[lane + 64] = ldsC[lane + 64];
    }
}

// ---------------- fused gamma + expand (R7 form) ----------------
__global__ __launch_bounds__(256) void gamma_expand_kernel(
        const float* __restrict__ pa, const float* __restrict__ pb,
        const float* __restrict__ ca, const float* __restrict__ cb,
        const float* __restrict__ text, const float* __restrict__ mmask,
        float* __restrict__ gamma_out, float* __restrict__ expanded) {
    __shared__ float wt[II][9];
    __shared__ float Ei[II];
    __shared__ float red[8][33];
    int b   = blockIdx.x >> 6;
    int jj0 = (blockIdx.x & 63) * 8;
    int t = threadIdx.x;
    int q = t & 7, ic = t >> 3;

    if (t < II) Ei[t] = ca[b*II + t] + cb[b*II + t];
    __syncthreads();
    float maxc = Ei[0];
    #pragma unroll 16
    for (int i = 1; i < II; ++i) maxc = fmaxf(maxc, Ei[i]);
    __syncthreads();
    if (t < II) Ei[t] = __expf(Ei[t] - maxc);
    __syncthreads();

    size_t idx0  = (size_t)b * II * JJ + jj0 + q;
    size_t idx0r = (size_t)b * II * JJ + (JJ - 1 - jj0 - q);   // pb stored j-reversed
    float d = 0.f;
    #pragma unroll
    for (int k = 0; k < 4; ++k) {
        int i = ic * 4 + k;
        float P = pa[idx0 + (size_t)i * JJ] * pb[idx0r + (size_t)i * JJ] * Ei[i];
        wt[i][q] = P;
        d += P;
    }
    red[q][ic] = d;
    __syncthreads();
    if (t < 8) {
        float s = 0.f;
        #pragma unroll
        for (int k = 0; k < 32; ++k) s += red[t][k];
        red[t][32] = 1.0f / fmaxf(s, 1e-37f);
    }
    __syncthreads();
    float rD = red[q][32];
    #pragma unroll
    for (int k = 0; k < 4; ++k) {
        int i = ic * 4 + k;
        float P = wt[i][q] * rD;
        wt[i][q] = P;
        gamma_out[idx0 + (size_t)i * JJ] = fmaxf(__logf(P), -1e30f);
    }
    __syncthreads();

    float acc[8] = {0,0,0,0,0,0,0,0};
    const float* txb = text + (size_t)b * II * CC + t;
    #pragma unroll 4
    for (int i = 0; i < II; ++i) {
        float tv = txb[(size_t)i * CC];
        #pragma unroll
        for (int qq = 0; qq < 8; ++qq) acc[qq] = fmaf(wt[i][qq], tv, acc[qq]);
    }
    #pragma unroll
    for (int qq = 0; qq < 8; ++qq) {
        expanded[(size_t)(b * JJ + jj0 + qq) * CC + t] =
            acc[qq] * mmask[b * JJ + jj0 + qq];
    }
}

extern "C" void kernel_launch(void* const* d_in, const int* in_sizes, int n_in,
                              void* d_out, int out_size, void* d_ws, size_t ws_size,
                              hipStream_t stream) {
    const float* text  = (const float*)d_in[0];
    const float* mel   = (const float*)d_in[1];
    const float* mmask = (const float*)d_in[3];
    const float* noise = (const float*)d_in[4];
    const float* ratio = (const float*)d_in[5];
    float* gamma_out = (float*)d_out;            // B*I*J floats
    float* expanded  = (float*)d_out + NEL;      // B*J*C floats

    float* ws = (float*)d_ws;
    float* Ee = ws;                  // NEL
    float* Wa = ws +   NEL;          // NEL
    float* Wb = ws + 2*NEL;          // NEL
    float* pa = ws + 3*NEL;          // NEL (aliased: e lives here pre-scan)
    float* pb = ws + 4*NEL;          // NEL (j-reversed layout)
    float* ca = ws + 5*NEL;          // BB*II
    float* cb = ws + 5*NEL + BB*II;  // BB*II
    float* e  = pa;                  // e dead once scan_ab starts writing pa

    hipLaunchKernelGGL(energy_kernel, dim3(BB, II/8, JJ/64), dim3(256), 0, stream,
                       text, mel, noise, ratio, e);
    hipLaunchKernelGGL(dscan_kernel, dim3(BB*II), dim3(64), 0, stream, e, Ee, Wa, Wb);
    hipLaunchKernelGGL(scan_ab_kernel, dim3(BB*2), dim3(320), 0, stream,
                       Ee, Wa, Wb, pa, pb, ca, cb);
    hipLaunchKernelGGL(gamma_expand_kernel, dim3(BB*64), dim3(256), 0, stream,
                       pa, pb, ca, cb, text, mmask, gamma_out, expanded);
}